// Round 4
// baseline (259.655 us; speedup 1.0000x reference)
//
#include <hip/hip_runtime.h>
#include <hip/hip_bf16.h>

// TextualContrastiveLoss: B=4096, D=1024, NUM_CLASSES=100, T=0.5
//   z = l2norm(emb); reps = [z_i; z_j] (8192x1024)
//   sim = reps @ reps^T; e = exp(sim/T) with diag excluded
//   loss = mean_n( log(sum_m e) - log(sum_{m: lab match} e) )
//
// R1: fused 128x128 MFMA GEMM, 353 TF — 16-way LDS bank conflicts.
// R2: XOR swizzle -> conflicts 0, only -6% (latency-bound).
// R3: symmetry: upper-tri tiles only, dual row/col scatter. 171us, 408 TF.
//     Still latency-bound: K=1024 -> only 16 iters/block, fixed costs
//     (barrier drains, epilogue) don't amortize; 1.06 GB staged.
// R4: 256x256 tiles, 1024 thr (16 waves of 64x64), mfma 32x32x16.
//     4x FLOP per barrier/epilogue event, 1/2 staged bytes per FLOP.
//     LDS = A+B = 64 KB exactly; labels read from global in epilogue.
//     528 blocks, 1 block/CU (VGPR-bound), HW backfill load-balances.

#define BHALF 4096
#define N2 8192
#define DK 1024
#define TILE 256
#define BK 64
#define NT 32                 // 8192/256 tile rows
#define NTILES 528            // 32*33/2

typedef __attribute__((ext_vector_type(16))) float f32x16;
typedef __attribute__((ext_vector_type(8))) short bf16x8;
typedef unsigned short u16;

// exp(s/0.5) = exp2(s * 2*log2(e))
#define EXP_SCALE 2.8853900817779268f

static __device__ inline u16 f2bf_rne(float x) {
    unsigned u = __builtin_bit_cast(unsigned, x);
    unsigned r = (u + 0x7fff + ((u >> 16) & 1)) >> 16;
    return (u16)r;
}

__global__ __launch_bounds__(256) void normalize_kernel(
    const float* __restrict__ emb_i, const float* __restrict__ emb_j,
    u16* __restrict__ reps, float* __restrict__ nomden,
    float* __restrict__ out) {
    int r = blockIdx.x;           // 0..8191
    int t = threadIdx.x;          // 0..255, one float4 each
    int idx = r * 256 + t;
    if (idx < 2 * N2) nomden[idx] = 0.0f;     // fused zero of nom+den
    if (idx == 0) out[0] = 0.0f;
    const float* src = (r < BHALF) ? (emb_i + (size_t)r * DK)
                                   : (emb_j + (size_t)(r - BHALF) * DK);
    float4 v = ((const float4*)src)[t];
    float s = v.x * v.x + v.y * v.y + v.z * v.z + v.w * v.w;
#pragma unroll
    for (int m = 1; m <= 32; m <<= 1) s += __shfl_xor(s, m, 64);
    __shared__ float red[4];
    if ((t & 63) == 0) red[t >> 6] = s;
    __syncthreads();
    float tot = red[0] + red[1] + red[2] + red[3];
    float scale = 1.0f / fmaxf(sqrtf(tot), 1e-12f);
    ushort4 o;
    o.x = f2bf_rne(v.x * scale);
    o.y = f2bf_rne(v.y * scale);
    o.z = f2bf_rne(v.z * scale);
    o.w = f2bf_rne(v.w * scale);
    ((ushort4*)(reps + (size_t)r * DK))[t] = o;
}

__global__ __launch_bounds__(1024) void gemm_loss_kernel(
    const u16* __restrict__ reps, const int* __restrict__ labels,
    float* __restrict__ nom, float* __restrict__ den) {
    // LDS: A 256x64 bf16 (32KB) + B 256x64 (32KB) = 64 KB exactly.
    // XOR swizzle: slot (row, cb_lds) holds global col-block cb_lds^(row&7)
    __shared__ __align__(16) u16 A_s[TILE * BK];
    __shared__ __align__(16) u16 B_s[TILE * BK];

    // upper-triangle decode: row-major over bi<=bj
    int rem = blockIdx.x;
    int bi = 0;
    while (rem >= NT - bi) { rem -= NT - bi; ++bi; }
    int bj = bi + rem;
    int rowBase = bi * TILE;
    int colBase = bj * TILE;

    int tid = threadIdx.x;
    int w = tid >> 6;             // wave 0..15 -> 4x4 grid of 64x64 subtiles
    int lane = tid & 63;
    int wm = w >> 2, wn = w & 3;
    int half = lane >> 5;         // K-half selector for 32x32x16 frags
    int l31 = lane & 31;

    f32x16 acc[2][2];
#pragma unroll
    for (int i = 0; i < 2; ++i)
#pragma unroll
        for (int j = 0; j < 2; ++j)
#pragma unroll
            for (int r = 0; r < 16; ++r) acc[i][j][r] = 0.0f;

    // staging: lane l -> LDS slot (l>>3, l&7) within its 1KB chunk;
    // lane fetches global col-block (l&7)^(l>>3) to realize the swizzle
    int srow = lane >> 3;                       // 0..7 (row within chunk)
    int scol = ((lane & 7) ^ srow) * 8;         // swizzled element col

    for (int kt = 0; kt < DK / BK; ++kt) {
        int k0 = kt * BK;
        // 32 chunks each for A and B; wave w stages chunks {2w, 2w+1}
#pragma unroll
        for (int c = 0; c < 2; ++c) {
            int chunk = 2 * w + c;
            int r = chunk * 8 + srow;           // 0..255
            const u16* gpA = reps + (size_t)(rowBase + r) * DK + k0 + scol;
            const u16* gpB = reps + (size_t)(colBase + r) * DK + k0 + scol;
            __builtin_amdgcn_global_load_lds(
                (const __attribute__((address_space(1))) void*)gpA,
                (__attribute__((address_space(3))) void*)&A_s[chunk * 512], 16, 0, 0);
            __builtin_amdgcn_global_load_lds(
                (const __attribute__((address_space(1))) void*)gpB,
                (__attribute__((address_space(3))) void*)&B_s[chunk * 512], 16, 0, 0);
        }
        __syncthreads();
        // 4 K-steps of 16; A frag (32x32x16): row=lane&31, k=(lane>>5)*8+j
#pragma unroll
        for (int s = 0; s < 4; ++s) {
            int cb = s * 2 + half;              // global col-block of frag
            bf16x8 aF[2], bF[2];
#pragma unroll
            for (int ti = 0; ti < 2; ++ti) {
                int ra = wm * 64 + ti * 32 + l31;
                aF[ti] = *(const bf16x8*)&A_s[ra * BK + ((cb ^ (ra & 7)) << 3)];
                int rb = wn * 64 + ti * 32 + l31;
                bF[ti] = *(const bf16x8*)&B_s[rb * BK + ((cb ^ (rb & 7)) << 3)];
            }
#pragma unroll
            for (int ti = 0; ti < 2; ++ti)
#pragma unroll
                for (int tj = 0; tj < 2; ++tj)
                    acc[ti][tj] = __builtin_amdgcn_mfma_f32_32x32x16_bf16(
                        aF[ti], bF[tj], acc[ti][tj], 0, 0, 0);
        }
        __syncthreads();
    }

    // Epilogue. 32x32 C/D layout (m74/m101-verified):
    //   col = lane&31, row = (reg&3) + 8*(reg>>2) + 4*(lane>>5)
    bool offd = (bi != bj);
    int lc[2], gcol[2];
#pragma unroll
    for (int tj = 0; tj < 2; ++tj) {
        gcol[tj] = colBase + wn * 64 + tj * 32 + l31;
        lc[tj] = labels[gcol[tj] & (BHALF - 1)];   // 16KB table, L1-hot
    }
    float colD[2] = {0.f, 0.f}, colN[2] = {0.f, 0.f};
#pragma unroll
    for (int ti = 0; ti < 2; ++ti) {
#pragma unroll
        for (int r = 0; r < 16; ++r) {
            int rowIn = (r & 3) + 8 * (r >> 2) + 4 * half;
            int grow = rowBase + wm * 64 + ti * 32 + rowIn;
            int labr = labels[grow & (BHALF - 1)];
            float rD = 0.f, rN = 0.f;
#pragma unroll
            for (int tj = 0; tj < 2; ++tj) {
                float e = exp2f(acc[ti][tj][r] * EXP_SCALE);
                if (grow == gcol[tj]) e = 0.f;     // diag (only when bi==bj)
                bool m = (lc[tj] == labr);
                rD += e; if (m) rN += e;
                colD[tj] += e; if (m) colN[tj] += e;
            }
            // reduce row sums across the 32 column-lanes of this half
#pragma unroll
            for (int msk = 1; msk <= 16; msk <<= 1) {
                rD += __shfl_xor(rD, msk, 64);
                rN += __shfl_xor(rN, msk, 64);
            }
            if (l31 == 0) {       // lanes 0 and 32 own distinct rows
                atomicAdd(&den[grow], rD);
                atomicAdd(&nom[grow], rN);
            }
        }
    }
    if (offd) {
        // symmetric counterpart: column sums scattered as row sums of (c,r)
#pragma unroll
        for (int tj = 0; tj < 2; ++tj) {
            float cd = colD[tj] + __shfl_xor(colD[tj], 32, 64);
            float cn = colN[tj] + __shfl_xor(colN[tj], 32, 64);
            if (half == 0) {
                atomicAdd(&den[gcol[tj]], cd);
                atomicAdd(&nom[gcol[tj]], cn);
            }
        }
    }
}

__global__ __launch_bounds__(256) void finalize_kernel(
    const float* __restrict__ nom, const float* __restrict__ den,
    float* __restrict__ out) {
    int idx = blockIdx.x * 256 + threadIdx.x;   // 32 blocks x 256
    int t = threadIdx.x;
    float s = 0.f;
    if (idx < N2) s = logf(den[idx]) - logf(nom[idx]);   // -log(nom/den)
#pragma unroll
    for (int m = 1; m <= 32; m <<= 1) s += __shfl_xor(s, m, 64);
    __shared__ float red[4];
    if ((t & 63) == 0) red[t >> 6] = s;
    __syncthreads();
    if (t == 0)
        atomicAdd(out, (red[0] + red[1] + red[2] + red[3]) / (float)N2);
}

extern "C" void kernel_launch(void* const* d_in, const int* in_sizes, int n_in,
                              void* d_out, int out_size, void* d_ws, size_t ws_size,
                              hipStream_t stream) {
    const float* emb_i = (const float*)d_in[0];
    const float* emb_j = (const float*)d_in[1];
    const int* labels  = (const int*)d_in[2];
    float* out = (float*)d_out;

    char* ws = (char*)d_ws;
    u16* reps  = (u16*)ws;                                  // 16 MB
    float* nom = (float*)(ws + (size_t)N2 * DK * 2);        // 32 KB
    float* den = nom + N2;                                  // 32 KB

    normalize_kernel<<<N2, 256, 0, stream>>>(emb_i, emb_j, reps, nom, out);
    gemm_loss_kernel<<<NTILES, 1024, 0, stream>>>(reps, labels, nom, den);
    finalize_kernel<<<(N2 + 255) / 256, 256, 0, stream>>>(nom, den, out);
}